// Round 15
// baseline (456.907 us; speedup 1.0000x reference)
//
#include <hip/hip_runtime.h>
#include <hip/hip_bf16.h>
#include <math.h>

#define NN 50000
#define EE 800000
#define NT (EE / 16)          // 50000 flat 16-edge tiles (exact)
#define NTN (NN / 16)         // 3125 node tiles

// edge_mfma64 + edge_mfma16: 1536 blocks = exactly 6/CU; balanced wave
// partition. HARD RULES (R1-R14): (1) natural VGPR ~72-80; ANY launch_bounds
// min-waves cap -> bimodal allocator -> full spill (R3/R6). (2) no unroll-2.
// (3) no inline-asm cvt_pk (R4) -- but native __bf16 cast IS the win (R9).
// (4) no readfirstlane scan (R7). (5) carried two-level register scan (R8/R9).
// (6) edge-kernel inner loops are FROZEN. (7) prep_k grid-union (R12/R13).
// (8) 2-dispatch scan + folded st-zero (R14).
// R15: bn-kernel occupancy. The bn_a0_*/bn_stats family inherited NBF=196
// blocks (0.77 blocks/CU, 12.5% occupancy) -- latency-starved for streaming
// kernels moving ~45 MB each. Grid raised to NBB=512 (stride NWB=2048);
// wave-stride loop keeps coverage exact. bn_stats 256 -> 512 (dynamic stride).
#define NBLK64 1536
#define NW64 (NBLK64 * 4)     // 6144 waves
#define B64 (NT / NW64)       // 8
#define R64 (NT % NW64)       // 848

// prep_k cvt path keeps the 196-block partition (R12 union layout)
#define NBF 196
#define NWF (NBF * 4)         // 784 waves
#define NBCNT (EE / 256)      // 3125 count blocks (exact)
#define NBPREP (NBF + NBCNT)  // 3321 union blocks

// R15: bn kernels get their own (larger) grid
#define NBB 512
#define NWB (NBB * 4)         // 2048 waves

typedef short s8v __attribute__((ext_vector_type(8)));   // 8 x bf16 (4 VGPRs)
typedef float f4v __attribute__((ext_vector_type(4)));   // MFMA C/D

// fp32 -> bf16 RNE via the native __bf16 type: lowers to the HW converter
// (v_cvt_pk_bf16_f32 pairs under SLP) instead of a 4-op bit sequence. (R9 win)
__device__ __forceinline__ short f2bf(float f) {
    __bf16 h = (__bf16)f;
    return __builtin_bit_cast(short, h);
}

// monotone fp32 <-> uint encode for atomicMax-based segment max.
// key 0 (memset) < enc(any float) -> "never touched" -> decodes to 0.
__device__ __forceinline__ unsigned enc(float f) {
    unsigned u = __float_as_uint(f);
    return (u & 0x80000000u) ? ~u : (u | 0x80000000u);
}
__device__ __forceinline__ float dec(unsigned k) {
    if (k == 0u) return 0.0f;                            // empty segment -> 0
    unsigned u = (k & 0x80000000u) ? (k & 0x7fffffffu) : ~k;
    return __uint_as_float(u);
}

// mish(x) = x * (e^{2x}+2e^x) / (e^{2x}+2e^x+2); guard large x
__device__ __forceinline__ float mish_fast(float v) {
    float t = __expf(v);
    float s = t * (t + 2.0f);
    float r = v * s * __builtin_amdgcn_rcpf(s + 2.0f);
    return (v > 15.0f) ? v : r;
}

#define MFMA16(a, b, c) __builtin_amdgcn_mfma_f32_16x16x32_bf16(a, b, c, 0, 0, 0)

// ---------------- CSR build (dst-sorted edge list, int2 interleaved) -------

#define NBS 196                                    // ceil(NN/256)

// per-256-chunk partial sums; block 0 also zeroes the BN-stats accumulator
__global__ __launch_bounds__(256) void scan_part(const int* __restrict__ cnt,
                                                 int* __restrict__ part,
                                                 float* __restrict__ st) {
    int t = threadIdx.x, i = blockIdx.x * 256 + t;
    if (blockIdx.x == 0) {
        st[t] = 0.0f;
        if (t < 128) st[256 + t] = 0.0f;           // 3*128 = 384 floats total
    }
    __shared__ int ps[256];
    ps[t] = (i < NN) ? cnt[i] : 0;
    __syncthreads();
    for (int off = 128; off > 0; off >>= 1) {
        if (t < off) ps[t] += ps[t + off];
        __syncthreads();
    }
    if (t == 0) part[blockIdx.x] = ps[0];
}

// R14: scan_top folded in -- every block recomputes the 196-partial prefix
__global__ __launch_bounds__(256) void scan_fin(const int* __restrict__ cnt,
                                                const int* __restrict__ part,
                                                int* __restrict__ row_off) {
    int t = threadIdx.x, i = blockIdx.x * 256 + t;
    __shared__ int pp[256];
    pp[t] = (t < NBS) ? part[t] : 0;
    __syncthreads();
    for (int off = 1; off < 256; off <<= 1) {
        int u = (t >= off) ? pp[t - off] : 0;
        __syncthreads();
        pp[t] += u;
        __syncthreads();
    }
    const int base = (blockIdx.x == 0) ? 0 : pp[blockIdx.x - 1];  // excl prefix

    int v = (i < NN) ? cnt[i] : 0;
    __shared__ int ps[256];
    ps[t] = v;
    __syncthreads();
    for (int off = 1; off < 256; off <<= 1) {
        int u = (t >= off) ? ps[t - off] : 0;
        __syncthreads();
        ps[t] += u;
        __syncthreads();
    }
    int excl = ps[t] - v + base;
    if (i < NN) row_off[i] = excl;
}

// atomic-FREE scatter: position from cached row_off + precomputed rank (R11)
__global__ __launch_bounds__(256) void scatter_k(const int* __restrict__ ei,
                                                 const int* __restrict__ row_off,
                                                 const int* __restrict__ rank,
                                                 int2* __restrict__ csr_sd) {
    int e = blockIdx.x * 256 + threadIdx.x;
    if (e < EE) {
        int d = ei[EE + e];
        int p = row_off[d] + rank[e];
        int2 v;
        v.x = ei[e];                               // src
        v.y = d;                                   // dst
        csr_sd[p] = v;
    }
}

// -------- R12 grid-union: cvt_a0 (blocks < NBF) U count_rank (rest) --------

__global__ __launch_bounds__(256)
void prep_k(const float* __restrict__ x, const float* __restrict__ w1,
            const float* __restrict__ b1, const int* __restrict__ ei,
            unsigned short* __restrict__ xb, float* __restrict__ a0,
            unsigned* __restrict__ y, unsigned* __restrict__ y8,
            int* __restrict__ cnt, int* __restrict__ rank) {
    const int tid = threadIdx.x;

    if (blockIdx.x >= NBF) {                       // ---- count_rank path ----
        int e = (blockIdx.x - NBF) * 256 + tid;    // < EE exactly (3125*256)
        rank[e] = atomicAdd(&cnt[ei[EE + e]], 1);
        return;
    }

    // ---- cvt_a0 path (R11 verbatim) ----
    const int lane = tid & 63;
    const int wid = blockIdx.x * 4 + (tid >> 6);
    const int i = lane & 15, q = lane >> 4;
    s8v wf[4][2];
#pragma unroll
    for (int nb = 0; nb < 4; nb++)
#pragma unroll
        for (int kh = 0; kh < 2; kh++)
#pragma unroll
            for (int j = 0; j < 8; j++) {
                int k = kh * 32 + q * 8 + j, n = nb * 16 + i;
                wf[nb][kh][j] = f2bf(w1[k * 64 + n] - w1[(64 + k) * 64 + n]);
            }
    float bia[4];
#pragma unroll
    for (int nb = 0; nb < 4; nb++) bia[nb] = b1[nb * 16 + i];

    for (int t = wid; t < NTN; t += NWF) {
        const int row = t * 16 + i;
        const float* xr = x + (size_t)row * 64 + q * 8;
        f4v x0 = *(const f4v*)xr,        f1 = *(const f4v*)(xr + 4);
        f4v x2 = *(const f4v*)(xr + 32), x3 = *(const f4v*)(xr + 36);
        s8v af0, af1;
#pragma unroll
        for (int j = 0; j < 4; j++) {
            af0[j] = f2bf(x0[j]); af0[4 + j] = f2bf(f1[j]);
            af1[j] = f2bf(x2[j]); af1[4 + j] = f2bf(x3[j]);
        }
        unsigned short* xw = xb + (size_t)row * 64 + q * 8;
        *(s8v*)xw = af0;
        *(s8v*)(xw + 32) = af1;
        const int rowq = t * 16 + q * 4;
#pragma unroll
        for (int nb = 0; nb < 4; nb++) {
            f4v c = {0.f, 0.f, 0.f, 0.f};
            c = MFMA16(af0, wf[nb][0], c);
            c = MFMA16(af1, wf[nb][1], c);
#pragma unroll
            for (int r = 0; r < 4; r++)
                a0[(size_t)(rowq + r) * 64 + i * 4 + nb] = c[r] + bia[nb];
        }
    }
    // zero the atomic-max accumulators (uint4)
    const int gt = blockIdx.x * 256 + tid, gs = NBF * 256;
    const uint4 z4 = {0u, 0u, 0u, 0u};
    uint4* y4 = (uint4*)y;
    uint4* y84 = (uint4*)y8;
    for (int idx = gt; idx < NN * 16; idx += gs) y4[idx] = z4;   // NN*64 uints
    for (int idx = gt; idx < NN * 2; idx += gs)  y84[idx] = z4;  // NN*8 uints
}

// -------- fused BN apply + bf16 emit + NEXT layer's a0 GEMM + y re-zero ----
// R15: NBB-block grid (stride NWB) for latency hiding.

__global__ __launch_bounds__(256)
void bn_a0_64(unsigned* __restrict__ yk, const float* __restrict__ st,
              const float* __restrict__ g, const float* __restrict__ be,
              const float* __restrict__ w1n, const float* __restrict__ b1n,
              unsigned short* __restrict__ xbout, float* __restrict__ a0out) {
    __shared__ float sa[64], sb[64];
    const int tid = threadIdx.x;
    if (tid < 64) {
        float mu  = st[tid] * (1.0f / NN);
        float var = st[64 + tid] * (1.0f / NN) - mu * mu;
        float sc  = rsqrtf(var + 1e-5f) * g[tid];
        sa[tid] = sc;
        sb[tid] = be[tid] - mu * sc;
    }
    __syncthreads();
    const int lane = tid & 63;
    const int wid = blockIdx.x * 4 + (tid >> 6);
    const int i = lane & 15, q = lane >> 4;

    s8v wf[4][2];
#pragma unroll
    for (int nb = 0; nb < 4; nb++)
#pragma unroll
        for (int kh = 0; kh < 2; kh++)
#pragma unroll
            for (int j = 0; j < 8; j++) {
                int k = kh * 32 + q * 8 + j, n = nb * 16 + i;
                wf[nb][kh][j] = f2bf(w1n[k * 64 + n] - w1n[(64 + k) * 64 + n]);
            }
    float bia[4];
#pragma unroll
    for (int nb = 0; nb < 4; nb++) bia[nb] = b1n[nb * 16 + i];

    // per-lane norm constants for its 16 channels (k = kh*32 + q*8 + j)
    f4v a00 = *(const f4v*)(sa + q * 8),      a01 = *(const f4v*)(sa + q * 8 + 4);
    f4v a10 = *(const f4v*)(sa + 32 + q * 8), a11 = *(const f4v*)(sa + 36 + q * 8);
    f4v b00 = *(const f4v*)(sb + q * 8),      b01 = *(const f4v*)(sb + q * 8 + 4);
    f4v b10 = *(const f4v*)(sb + 32 + q * 8), b11 = *(const f4v*)(sb + 36 + q * 8);

    const uint4 z4 = {0u, 0u, 0u, 0u};
    for (int t = wid; t < NTN; t += NWB) {
        const int row = t * 16 + i;
        unsigned* yr = yk + (size_t)row * 64 + q * 8;
        uint4 u0 = *(const uint4*)yr,        u1 = *(const uint4*)(yr + 4);
        uint4 u2 = *(const uint4*)(yr + 32), u3 = *(const uint4*)(yr + 36);
        s8v af0, af1;
        af0[0] = f2bf(dec(u0.x) * a00[0] + b00[0]);
        af0[1] = f2bf(dec(u0.y) * a00[1] + b00[1]);
        af0[2] = f2bf(dec(u0.z) * a00[2] + b00[2]);
        af0[3] = f2bf(dec(u0.w) * a00[3] + b00[3]);
        af0[4] = f2bf(dec(u1.x) * a01[0] + b01[0]);
        af0[5] = f2bf(dec(u1.y) * a01[1] + b01[1]);
        af0[6] = f2bf(dec(u1.z) * a01[2] + b01[2]);
        af0[7] = f2bf(dec(u1.w) * a01[3] + b01[3]);
        af1[0] = f2bf(dec(u2.x) * a10[0] + b10[0]);
        af1[1] = f2bf(dec(u2.y) * a10[1] + b10[1]);
        af1[2] = f2bf(dec(u2.z) * a10[2] + b10[2]);
        af1[3] = f2bf(dec(u2.w) * a10[3] + b10[3]);
        af1[4] = f2bf(dec(u3.x) * a11[0] + b11[0]);
        af1[5] = f2bf(dec(u3.y) * a11[1] + b11[1]);
        af1[6] = f2bf(dec(u3.z) * a11[2] + b11[2]);
        af1[7] = f2bf(dec(u3.w) * a11[3] + b11[3]);

        unsigned short* xw = xbout + (size_t)row * 64 + q * 8;
        *(s8v*)xw = af0;
        *(s8v*)(xw + 32) = af1;
        *(uint4*)yr = z4;        *(uint4*)(yr + 4) = z4;    // re-zero for next layer
        *(uint4*)(yr + 32) = z4; *(uint4*)(yr + 36) = z4;

        const int rowq = t * 16 + q * 4;
#pragma unroll
        for (int nb = 0; nb < 4; nb++) {
            f4v c = {0.f, 0.f, 0.f, 0.f};
            c = MFMA16(af0, wf[nb][0], c);
            c = MFMA16(af1, wf[nb][1], c);
#pragma unroll
            for (int r = 0; r < 4; r++)
                a0out[(size_t)(rowq + r) * 64 + i * 4 + nb] = c[r] + bia[nb];
        }
    }
}

// variant for layer 2 -> 3: next layer dout = 8 (R15: NWB stride)

__global__ __launch_bounds__(256)
void bn_a0_8(unsigned* __restrict__ yk, const float* __restrict__ st,
             const float* __restrict__ g, const float* __restrict__ be,
             const float* __restrict__ w1n, const float* __restrict__ b1n,
             unsigned short* __restrict__ xbout, float* __restrict__ a08) {
    __shared__ float sa[64], sb[64];
    const int tid = threadIdx.x;
    if (tid < 64) {
        float mu  = st[tid] * (1.0f / NN);
        float var = st[64 + tid] * (1.0f / NN) - mu * mu;
        float sc  = rsqrtf(var + 1e-5f) * g[tid];
        sa[tid] = sc;
        sb[tid] = be[tid] - mu * sc;
    }
    __syncthreads();
    const int lane = tid & 63;
    const int wid = blockIdx.x * 4 + (tid >> 6);
    const int i = lane & 15, q = lane >> 4;

    s8v wf[2];
#pragma unroll
    for (int kh = 0; kh < 2; kh++)
#pragma unroll
        for (int j = 0; j < 8; j++) {
            int k = kh * 32 + q * 8 + j;
            wf[kh][j] = (i < 8) ? f2bf(w1n[k * 8 + i] - w1n[(64 + k) * 8 + i]) : (short)0;
        }
    const float bia = (i < 8) ? b1n[i] : 0.0f;

    f4v a00 = *(const f4v*)(sa + q * 8),      a01 = *(const f4v*)(sa + q * 8 + 4);
    f4v a10 = *(const f4v*)(sa + 32 + q * 8), a11 = *(const f4v*)(sa + 36 + q * 8);
    f4v b00 = *(const f4v*)(sb + q * 8),      b01 = *(const f4v*)(sb + q * 8 + 4);
    f4v b10 = *(const f4v*)(sb + 32 + q * 8), b11 = *(const f4v*)(sb + 36 + q * 8);

    for (int t = wid; t < NTN; t += NWB) {
        const int row = t * 16 + i;
        const unsigned* yr = yk + (size_t)row * 64 + q * 8;
        uint4 u0 = *(const uint4*)yr,        u1 = *(const uint4*)(yr + 4);
        uint4 u2 = *(const uint4*)(yr + 32), u3 = *(const uint4*)(yr + 36);
        s8v af0, af1;
        af0[0] = f2bf(dec(u0.x) * a00[0] + b00[0]);
        af0[1] = f2bf(dec(u0.y) * a00[1] + b00[1]);
        af0[2] = f2bf(dec(u0.z) * a00[2] + b00[2]);
        af0[3] = f2bf(dec(u0.w) * a00[3] + b00[3]);
        af0[4] = f2bf(dec(u1.x) * a01[0] + b01[0]);
        af0[5] = f2bf(dec(u1.y) * a01[1] + b01[1]);
        af0[6] = f2bf(dec(u1.z) * a01[2] + b01[2]);
        af0[7] = f2bf(dec(u1.w) * a01[3] + b01[3]);
        af1[0] = f2bf(dec(u2.x) * a10[0] + b10[0]);
        af1[1] = f2bf(dec(u2.y) * a10[1] + b10[1]);
        af1[2] = f2bf(dec(u2.z) * a10[2] + b10[2]);
        af1[3] = f2bf(dec(u2.w) * a10[3] + b10[3]);
        af1[4] = f2bf(dec(u3.x) * a11[0] + b11[0]);
        af1[5] = f2bf(dec(u3.y) * a11[1] + b11[1]);
        af1[6] = f2bf(dec(u3.z) * a11[2] + b11[2]);
        af1[7] = f2bf(dec(u3.w) * a11[3] + b11[3]);

        unsigned short* xw = xbout + (size_t)row * 64 + q * 8;
        *(s8v*)xw = af0;
        *(s8v*)(xw + 32) = af1;

        f4v c = {0.f, 0.f, 0.f, 0.f};
        c = MFMA16(af0, wf[0], c);
        c = MFMA16(af1, wf[1], c);
        if (i < 8) {
            const int rowq = t * 16 + q * 4;
#pragma unroll
            for (int r = 0; r < 4; r++)
                a08[(size_t)(rowq + r) * 8 + i] = c[r] + bia;
        }
    }
}

// ------- edge-major fused MLP + segmented max, dout=64 (FROZEN R10) -------

__global__ __launch_bounds__(256)
void edge_mfma64(const unsigned short* __restrict__ xb, const float* __restrict__ a0,
                 const float* __restrict__ w1, const float* __restrict__ w2,
                 const float* __restrict__ b2,
                 const int2* __restrict__ csr_sd,
                 unsigned* __restrict__ y) {
    __shared__ float uld[4][16 * 68];                 // per-wave tile, stride 68
    __shared__ int dseg[4][2][20];                    // per-wave dst ids, dbuf
    __shared__ short w2l[8 * 64 * 8];                 // W2 frags: (nb*2+kh, lane, j)
    const int lane = threadIdx.x & 63;
    const int wv = threadIdx.x >> 6;
    const int wid = blockIdx.x * 4 + wv;
    const int i = lane & 15, q = lane >> 4;
    float* up = &uld[wv][0];
    float* spw = up;                                  // 4x64 partials alias (safe)

    // W1bot fragments stay register-resident (32 VGPRs)
    s8v w1f[4][2];
#pragma unroll
    for (int nb = 0; nb < 4; nb++)
#pragma unroll
        for (int kh = 0; kh < 2; kh++)
#pragma unroll
            for (int j = 0; j < 8; j++) {
                int k = kh * 32 + q * 8 + j, n = nb * 16 + i;
                w1f[nb][kh][j] = f2bf(w1[(64 + k) * 64 + n]);
            }
    // stage this wave's nb(=wv) W2 fragments into shared LDS
    {
        const int nb = wv;
#pragma unroll
        for (int kh = 0; kh < 2; kh++) {
            s8v uu;
#pragma unroll
            for (int j = 0; j < 8; j++) {
                int k = kh * 32 + q * 8 + j;
                uu[j] = f2bf(w2[k * 64 + nb * 16 + i]);
            }
            *(s8v*)(w2l + ((nb * 2 + kh) * 64 + lane) * 8) = uu;
        }
    }
    __syncthreads();

    const float b2s = b2[lane];                       // wave-scan channel = lane
    const float b2n0 = b2[i],      b2n1 = b2[16 + i]; // interior-flush channels
    const float b2n2 = b2[32 + i], b2n3 = b2[48 + i];

    // balanced partition: first R64 waves get B64+1 tiles, rest B64
    int t = wid * B64 + (wid < R64 ? wid : R64);
    const int tend = t + B64 + (wid < R64 ? 1 : 0);

    s8v af0_c, af1_c;
    {
        int s0 = csr_sd[t * 16 + i].x;
        const unsigned short* xr = xb + (size_t)s0 * 64;
        af0_c = *(const s8v*)(xr + q * 8);
        af1_c = *(const s8v*)(xr + 32 + q * 8);
    }
    int src_n = (t + 1 < tend) ? csr_sd[(t + 1) * 16 + i].x : 0;
    if (lane < 16) dseg[wv][t & 1][lane] = csr_sd[t * 16 + lane].y;
    asm volatile("s_waitcnt lgkmcnt(0)" ::: "memory");
    int dq_c[4];
#pragma unroll
    for (int r = 0; r < 4; r++) dq_c[r] = dseg[wv][t & 1][q * 4 + r];
    f4v a0r_c[4];
#pragma unroll
    for (int r = 0; r < 4; r++)
        a0r_c[r] = *(const f4v*)(a0 + (size_t)dq_c[r] * 64 + i * 4);

    // carried wave-scan state (channel = lane)
    float runC = -INFINITY;
    int dcC = dseg[wv][t & 1][0];

    for (; t < tend; t++) {
        const bool has_n = (t + 1) < tend;
        const int* dsg = &dseg[wv][t & 1][0];
        int* dsg_n = &dseg[wv][(t + 1) & 1][0];

        if (has_n && lane < 16) dsg_n[lane] = csr_sd[(t + 1) * 16 + lane].y;

        s8v af0_n = {0,0,0,0,0,0,0,0}, af1_n = {0,0,0,0,0,0,0,0};
        if (has_n) {
            const unsigned short* xr = xb + (size_t)src_n * 64;
            af0_n = *(const s8v*)(xr + q * 8);
            af1_n = *(const s8v*)(xr + 32 + q * 8);
        }
        int src_nn = (t + 2 < tend) ? csr_sd[(t + 2) * 16 + i].x : 0;

        // GEMM1
        f4v c0 = {0.f, 0.f, 0.f, 0.f}, c1 = c0, c2 = c0, c3 = c0;
        c0 = MFMA16(af0_c, w1f[0][0], c0); c0 = MFMA16(af1_c, w1f[0][1], c0);
        c1 = MFMA16(af0_c, w1f[1][0], c1); c1 = MFMA16(af1_c, w1f[1][1], c1);
        c2 = MFMA16(af0_c, w1f[2][0], c2); c2 = MFMA16(af1_c, w1f[2][1], c2);
        c3 = MFMA16(af0_c, w1f[3][0], c3); c3 = MFMA16(af1_c, w1f[3][1], c3);

        asm volatile("" ::: "memory");
        // stage-1: mish -> fp32 tile (R0 verbatim)
#pragma unroll
        for (int r = 0; r < 4; r++) {
            const int ro = (q * 4 + r) * 68 + i;
            up[ro +  0] = mish_fast(c0[r] + a0r_c[r][0]);
            up[ro + 16] = mish_fast(c1[r] + a0r_c[r][1]);
            up[ro + 32] = mish_fast(c2[r] + a0r_c[r][2]);
            up[ro + 48] = mish_fast(c3[r] + a0r_c[r][3]);
        }
        asm volatile("s_waitcnt lgkmcnt(0)" ::: "memory");   // stage1 + dsg_n visible

        int dq_n[4];
        f4v a0r_n[4];
        if (has_n) {
#pragma unroll
            for (int r = 0; r < 4; r++) dq_n[r] = dsg_n[q * 4 + r];
#pragma unroll
            for (int r = 0; r < 4; r++)
                a0r_n[r] = *(const f4v*)(a0 + (size_t)dq_n[r] * 64 + i * 4);
        }

        s8v uf[2];
#pragma unroll
        for (int kh = 0; kh < 2; kh++) {
            const f4v* rp = (const f4v*)(up + i * 68 + kh * 32 + q * 8);
            f4v v0 = rp[0], v1 = rp[1];
            s8v uu;
            uu[0] = f2bf(v0[0]); uu[1] = f2bf(v0[1]);
            uu[2] = f2bf(v0[2]); uu[3] = f2bf(v0[3]);
            uu[4] = f2bf(v1[0]); uu[5] = f2bf(v1[1]);
            uu[6] = f2bf(v1[2]); uu[7] = f2bf(v1[3]);
            uf[kh] = uu;
        }
        asm volatile("" ::: "memory");

        // GEMM2 (B fragments streamed from shared LDS); output stays in regs
        f4v cc[4];
#pragma unroll
        for (int nb = 0; nb < 4; nb++) {
            s8v b0 = *(const s8v*)(w2l + ((nb * 2 + 0) * 64 + lane) * 8);
            s8v b1v = *(const s8v*)(w2l + ((nb * 2 + 1) * 64 + lane) * 8);
            f4v c = {0.f, 0.f, 0.f, 0.f};
            c = MFMA16(uf[0], b0, c);
            c = MFMA16(uf[1], b1v, c);
            cc[nb] = c;
        }

        // in-register segmented reduce over this lane's 4 consecutive rows;
        // interior segment ends (rare) flush directly.
        float r0 = cc[0][0], r1 = cc[1][0], r2 = cc[2][0], r3 = cc[3][0];

#define SCAN_STEP(RR)                                                        \
        {                                                                    \
            bool mm = (dq_c[RR] != dq_c[RR - 1]);                            \
            if (__any(mm)) {                                                 \
                if (mm) {                                                    \
                    size_t bse = (size_t)dq_c[RR - 1] * 64 + i;              \
                    atomicMax(&y[bse],      enc(r0 + b2n0));                 \
                    atomicMax(&y[bse + 16], enc(r1 + b2n1));                 \
                    atomicMax(&y[bse + 32], enc(r2 + b2n2));                 \
                    atomicMax(&y[bse + 48], enc(r3 + b2n3));                 \
                }                                                            \
                r0 = mm ? cc[0][RR] : fmaxf(r0, cc[0][RR]);                  \
                r1 = mm ? cc[1][RR] : fmaxf(r1, cc[1][RR]);                  \
                r2 = mm ? cc[2][RR] : fmaxf(r2, cc[2][RR]);                  \
                r3 = mm ? cc[3][RR] : fmaxf(r3, cc[3][RR]);                  \
            } else {                                                         \
                r0 = fmaxf(r0, cc[0][RR]); r1 = fmaxf(r1, cc[1][RR]);        \
                r2 = fmaxf(r2, cc[2][RR]); r3 = fmaxf(r3, cc[3][RR]);        \
            }                                                                \
        }
        SCAN_STEP(1)
        SCAN_STEP(2)
        SCAN_STEP(3)
#undef SCAN_STEP

        // suffix partials -> 4x64 tile (aliases up: uf reads precede these
        // writes in program order; DS is in-order per wave), then carried
        // 4-step wave scan (channel = lane).
        spw[q * 68 +       i] = r0;
        spw[q * 68 + 16 +  i] = r1;
        spw[q * 68 + 32 +  i] = r2;
        spw[q * 68 + 48 +  i] = r3;
        asm volatile("s_waitcnt lgkmcnt(0)" ::: "memory");

        float v0 = spw[lane],        v1 = spw[68 + lane];
        float v2s = spw[136 + lane], v3s = spw[204 + lane];
        int e0 = dsg[3], e1 = dsg[7], e2 = dsg[11], e3 = dsg[15];

        if (e0 != dcC) {
            atomicMax(&y[(size_t)dcC * 64 + lane], enc(runC + b2s));
            runC = v0; dcC = e0;
        } else runC = fmaxf(runC, v0);
        if (e1 != dcC) {
            atomicMax(&y[(size_t)dcC * 64 + lane], enc(runC + b2s));
            runC = v1; dcC = e1;
        } else runC = fmaxf(runC, v1);
        if (e2 != dcC) {
            atomicMax(&y[(size_t)dcC * 64 + lane], enc(runC + b2s));
            runC = v2s; dcC = e2;
        } else runC = fmaxf(runC, v2s);
        if (e3 != dcC) {
            atomicMax(&y[(size_t)dcC * 64 + lane], enc(runC + b2s));
            runC = v3s; dcC = e3;
        } else runC = fmaxf(runC, v3s);
        asm volatile("s_waitcnt lgkmcnt(0)" ::: "memory");        // WAR guard

        src_n = src_nn;
        af0_c = af0_n; af1_c = af1_n;
#pragma unroll
        for (int r = 0; r < 4; r++) { dq_c[r] = dq_n[r]; a0r_c[r] = a0r_n[r]; }
    }
    // final flush of carried run
    atomicMax(&y[(size_t)dcC * 64 + lane], enc(runC + b2s));
}

// ------- edge-major final layer, dout=8 (FROZEN R10) -------

__global__ __launch_bounds__(256)
void edge_mfma16(const unsigned short* __restrict__ xb, const float* __restrict__ a0,
                 const float* __restrict__ w1, const float* __restrict__ w2,
                 const float* __restrict__ b2,
                 const int2* __restrict__ csr_sd,
                 unsigned* __restrict__ y8) {
    __shared__ float uld[4][16 * 20];
    __shared__ int dseg[4][2][16];
    const int lane = threadIdx.x & 63;
    const int wv = threadIdx.x >> 6;
    const int wid = blockIdx.x * 4 + wv;
    const int i = lane & 15, q = lane >> 4;
    float* up = &uld[wv][0];
    float* spw = up;                                  // 4x8 partials alias

    s8v w1f[2], w2f;
#pragma unroll
    for (int kh = 0; kh < 2; kh++)
#pragma unroll
        for (int j = 0; j < 8; j++) {
            int k = kh * 32 + q * 8 + j;
            w1f[kh][j] = (i < 8) ? f2bf(w1[(64 + k) * 8 + i]) : (short)0;
        }
#pragma unroll
    for (int j = 0; j < 8; j++)
        w2f[j] = (q == 0 && i < 8) ? f2bf(w2[j * 8 + i]) : (short)0;
    const float b2c = (lane < 8) ? b2[lane] : 0.0f;   // wave-scan channel
    const float b2n = (i < 8) ? b2[i] : 0.0f;         // interior-flush channel

    // balanced partition: first R64 waves get B64+1 tiles, rest B64
    int t = wid * B64 + (wid < R64 ? wid : R64);
    const int tend = t + B64 + (wid < R64 ? 1 : 0);

    s8v af0_c, af1_c;
    {
        int s0 = csr_sd[t * 16 + i].x;
        const unsigned short* xr = xb + (size_t)s0 * 64;
        af0_c = *(const s8v*)(xr + q * 8);
        af1_c = *(const s8v*)(xr + 32 + q * 8);
    }
    int src_n = (t + 1 < tend) ? csr_sd[(t + 1) * 16 + i].x : 0;
    if (lane < 16) dseg[wv][t & 1][lane] = csr_sd[t * 16 + lane].y;
    asm volatile("s_waitcnt lgkmcnt(0)" ::: "memory");
    int dq_c[4];
#pragma unroll
    for (int r = 0; r < 4; r++) dq_c[r] = dseg[wv][t & 1][q * 4 + r];
    float av_c[4];
#pragma unroll
    for (int r = 0; r < 4; r++)
        av_c[r] = (i < 8) ? a0[(size_t)dq_c[r] * 8 + i] : 0.0f;

    // carried wave-scan state (channel = lane&7, lanes<8 own the atomics)
    float runC = -INFINITY;
    int dcC = dseg[wv][t & 1][0];

    for (; t < tend; t++) {
        const bool has_n = (t + 1) < tend;
        const int* dsg = &dseg[wv][t & 1][0];
        int* dsg_n = &dseg[wv][(t + 1) & 1][0];

        if (has_n && lane < 16) dsg_n[lane] = csr_sd[(t + 1) * 16 + lane].y;

        s8v af0_n = {0,0,0,0,0,0,0,0}, af1_n = {0,0,0,0,0,0,0,0};
        if (has_n) {
            const unsigned short* xr = xb + (size_t)src_n * 64;
            af0_n = *(const s8v*)(xr + q * 8);
            af1_n = *(const s8v*)(xr + 32 + q * 8);
        }
        int src_nn = (t + 2 < tend) ? csr_sd[(t + 2) * 16 + i].x : 0;

        f4v c = {0.f, 0.f, 0.f, 0.f};
        c = MFMA16(af0_c, w1f[0], c);
        c = MFMA16(af1_c, w1f[1], c);

        asm volatile("" ::: "memory");
#pragma unroll
        for (int r = 0; r < 4; r++)
            up[(q * 4 + r) * 20 + i] = mish_fast(c[r] + av_c[r]);   // cols 8..15 = 0
        asm volatile("s_waitcnt lgkmcnt(0)" ::: "memory");           // wait#2

        int dq_n[4];
        float av_n[4] = {0, 0, 0, 0};
        if (has_n) {
#pragma unroll
            for (int r = 0; r < 4; r++) dq_n[r] = dsg_n[q * 4 + r];
#pragma unroll
            for (int r = 0; r < 4; r++)
                av_n[r] = (i < 8) ? a0[(size_t)dq_n[r] * 8 + i] : 0.0f;
        }

        s8v uf = {0,0,0,0,0,0,0,0};
        if (q < 2) {                                   // k = q*8+j < 16
            const f4v* rp = (const f4v*)(up + i * 20 + q * 8);
            f4v v0 = rp[0], v1 = rp[1];
            uf[0] = f2bf(v0[0]); uf[1] = f2bf(v0[1]);
            uf[2] = f2bf(v0[2]); uf[3] = f2bf(v0[3]);
            uf[4] = f2bf(v1[0]); uf[5] = f2bf(v1[1]);
            uf[6] = f2bf(v1[2]); uf[7] = f2bf(v1[3]);
        }
        asm volatile("" ::: "memory");

        f4v cc = {0.f, 0.f, 0.f, 0.f};
        cc = MFMA16(uf, w2f, cc);

        // in-register segmented reduce over this lane's 4 rows (ch = i, i<8)
        float r0 = cc[0];
#define SCAN16(RR)                                                           \
        {                                                                    \
            bool mm = (dq_c[RR] != dq_c[RR - 1]);                            \
            if (__any(mm)) {                                                 \
                if (mm && i < 8)                                             \
                    atomicMax(&y8[(size_t)dq_c[RR - 1] * 8 + i],             \
                              enc(r0 + b2n));                                \
                r0 = mm ? cc[RR] : fmaxf(r0, cc[RR]);                        \
            } else r0 = fmaxf(r0, cc[RR]);                                   \
        }
        SCAN16(1)
        SCAN16(2)
        SCAN16(3)
#undef SCAN16

        // suffix partial -> 4x8 tile (alias up rows 0-3), carried wave scan
        spw[q * 20 + i] = r0;
        asm volatile("s_waitcnt lgkmcnt(0)" ::: "memory");

        float v0 = spw[lane & 7],      v1 = spw[20 + (lane & 7)];
        float v2 = spw[40 + (lane & 7)], v3 = spw[60 + (lane & 7)];
        int e0 = dsg[3], e1 = dsg[7], e2 = dsg[11], e3 = dsg[15];

        if (e0 != dcC) {
            if (lane < 8) atomicMax(&y8[(size_t)dcC * 8 + lane], enc(runC + b2c));
            runC = v0; dcC = e0;
        } else runC = fmaxf(runC, v0);
        if (e1 != dcC) {
            if (lane < 8) atomicMax(&y8[(size_t)dcC * 8 + lane], enc(runC + b2c));
            runC = v1; dcC = e1;
        } else runC = fmaxf(runC, v1);
        if (e2 != dcC) {
            if (lane < 8) atomicMax(&y8[(size_t)dcC * 8 + lane], enc(runC + b2c));
            runC = v2; dcC = e2;
        } else runC = fmaxf(runC, v2);
        if (e3 != dcC) {
            if (lane < 8) atomicMax(&y8[(size_t)dcC * 8 + lane], enc(runC + b2c));
            runC = v3; dcC = e3;
        } else runC = fmaxf(runC, v3);
        asm volatile("s_waitcnt lgkmcnt(0)" ::: "memory");        // WAR guard

        src_n = src_nn;
        af0_c = af0_n; af1_c = af1_n;
#pragma unroll
        for (int r = 0; r < 4; r++) { dq_c[r] = dq_n[r]; av_c[r] = av_n[r]; }
    }
    if (lane < 8)
        atomicMax(&y8[(size_t)dcC * 8 + lane], enc(runC + b2c));
}

// ---------------- BatchNorm stats (R5: uint4-vectorized) ----------------
// thread (c4=(tid&15)*4, grp=tid>>4): 4 channels via one uint4 load/row.
// gridDim-dynamic stride: R15 launches 512 blocks for 2 blocks/CU.

__global__ __launch_bounds__(256)
void bn_stats(const unsigned* __restrict__ yk, float* __restrict__ st) {
    const int tid = threadIdx.x;
    const int c4 = (tid & 15) * 4;                 // channel group base
    const int grp = tid >> 4;                      // 16 row groups
    float s0 = 0, s1 = 0, s2 = 0, s3 = 0;
    float q0 = 0, q1 = 0, q2 = 0, q3 = 0;
    for (int n = blockIdx.x * 16 + grp; n < NN; n += gridDim.x * 16) {
        uint4 u = *(const uint4*)(yk + (size_t)n * 64 + c4);
        float v0 = dec(u.x), v1 = dec(u.y), v2 = dec(u.z), v3 = dec(u.w);
        s0 += v0; s1 += v1; s2 += v2; s3 += v3;
        q0 = fmaf(v0, v0, q0); q1 = fmaf(v1, v1, q1);
        q2 = fmaf(v2, v2, q2); q3 = fmaf(v3, v3, q3);
    }
    __shared__ float ls[256][4], lq[256][4];
    ls[tid][0] = s0; ls[tid][1] = s1; ls[tid][2] = s2; ls[tid][3] = s3;
    lq[tid][0] = q0; lq[tid][1] = q1; lq[tid][2] = q2; lq[tid][3] = q3;
    __syncthreads();
    if (tid < 64) {
        const int cg = tid >> 2, ce = tid & 3;     // channel = cg*4 + ce
        float ss = 0, qq = 0;
        for (int g = 0; g < 16; g++) {
            ss += ls[g * 16 + cg][ce];
            qq += lq[g * 16 + cg][ce];
        }
        atomicAdd(&st[cg * 4 + ce], ss);
        atomicAdd(&st[64 + cg * 4 + ce], qq);
    }
}

__global__ __launch_bounds__(256)
void decode_out(const unsigned* __restrict__ y8, float* __restrict__ out) {
    int idx = blockIdx.x * 256 + threadIdx.x;
    if (idx < NN * 8) out[idx] = dec(y8[idx]);
}

// ---------------- launch ----------------

extern "C" void kernel_launch(void* const* d_in, const int* in_sizes, int n_in,
                              void* d_out, int out_size, void* d_ws, size_t ws_size,
                              hipStream_t stream) {
    const float* x0 = (const float*)d_in[0];
    const int*   ei = (const int*)d_in[1];
    const float* w1[4] = {(const float*)d_in[3],  (const float*)d_in[9],
                          (const float*)d_in[15], (const float*)d_in[21]};
    const float* b1[4] = {(const float*)d_in[4],  (const float*)d_in[10],
                          (const float*)d_in[16], (const float*)d_in[22]};
    const float* w2[4] = {(const float*)d_in[5],  (const float*)d_in[11],
                          (const float*)d_in[17], (const float*)d_in[23]};
    const float* b2[4] = {(const float*)d_in[6],  (const float*)d_in[12],
                          (const float*)d_in[18], (const float*)d_in[24]};
    const float* gg[3] = {(const float*)d_in[7],  (const float*)d_in[13],
                          (const float*)d_in[19]};
    const float* be[3] = {(const float*)d_in[8],  (const float*)d_in[14],
                          (const float*)d_in[20]};

    char* p = (char*)d_ws;
    auto alloc = [&](size_t bytes) -> char* {
        char* r = p;
        p += (bytes + 255) & ~(size_t)255;
        return r;
    };
    int*      cnt     = (int*)alloc((size_t)NN * 4);
    int*      part    = (int*)alloc((size_t)NBS * 4);
    int*      row_off = (int*)alloc((size_t)(NN + 1) * 4);
    int*      rank    = (int*)alloc((size_t)EE * 4);
    int2*     csr_sd  = (int2*)alloc((size_t)EE * 8);
    float*    st      = (float*)alloc(3 * 128 * 4);
    float*    a0      = (float*)alloc((size_t)NN * 64 * 4);   // reused for a0_8
    unsigned* y       = (unsigned*)alloc((size_t)NN * 64 * 4);
    unsigned* y8      = (unsigned*)alloc((size_t)NN * 8 * 4);
    unsigned short* xb0 = (unsigned short*)alloc((size_t)NN * 64 * 2);
    unsigned short* xbA = (unsigned short*)alloc((size_t)NN * 64 * 2);
    unsigned short* xbB = xb0;

    hipMemsetAsync(cnt, 0, (size_t)NN * 4, stream);

    // R12 union dispatch: cvt_a0 (196 blocks) + count_rank (3125 blocks)
    prep_k<<<NBPREP, 256, 0, stream>>>(x0, w1[0], b1[0], ei, xb0, a0, y, y8,
                                       cnt, rank);

    // R14: 2-dispatch scan
    scan_part<<<NBS, 256, 0, stream>>>(cnt, part, st);
    scan_fin<<<NBS, 256, 0, stream>>>(cnt, part, row_off);
    scatter_k<<<(EE + 255) / 256, 256, 0, stream>>>(ei, row_off, rank, csr_sd);

    // layer 0
    edge_mfma64<<<NBLK64, 256, 0, stream>>>(xb0, a0, w1[0], w2[0], b2[0],
                                            csr_sd, y);
    bn_stats<<<512, 256, 0, stream>>>(y, st);
    bn_a0_64<<<NBB, 256, 0, stream>>>(y, st, gg[0], be[0], w1[1], b1[1], xbA, a0);

    // layer 1
    edge_mfma64<<<NBLK64, 256, 0, stream>>>(xbA, a0, w1[1], w2[1], b2[1],
                                            csr_sd, y);
    bn_stats<<<512, 256, 0, stream>>>(y, st + 128);
    bn_a0_64<<<NBB, 256, 0, stream>>>(y, st + 128, gg[1], be[1], w1[2], b1[2], xbB, a0);

    // layer 2
    edge_mfma64<<<NBLK64, 256, 0, stream>>>(xbB, a0, w1[2], w2[2], b2[2],
                                            csr_sd, y);
    bn_stats<<<512, 256, 0, stream>>>(y, st + 256);
    bn_a0_8<<<NBB, 256, 0, stream>>>(y, st + 256, gg[2], be[2], w1[3], b1[3], xbA, a0);

    // layer 3: xbA -> d_out [N,8]
    edge_mfma16<<<NBLK64, 256, 0, stream>>>(xbA, a0, w1[3], w2[3], b2[3],
                                            csr_sd, y8);
    decode_out<<<(NN * 8 + 255) / 256, 256, 0, stream>>>(y8, (float*)d_out);
}

// Round 16
// 442.234 us; speedup vs baseline: 1.0332x; 1.0332x over previous
//
#include <hip/hip_runtime.h>
#include <hip/hip_bf16.h>
#include <math.h>

#define NN 50000
#define EE 800000
#define NT (EE / 16)          // 50000 flat 16-edge tiles (exact)
#define NTN (NN / 16)         // 3125 node tiles

// FINAL (R16 = R14 verbatim, the best measured config: 442.9 us).
// Session ledger of counter-verified decisions:
//  R8: carried two-level register scan (kills 2nd LDS roundtrip)   -0.7us/disp
//  R9: native __bf16 cast (HW cvt, not 4-op bit-twiddle)           -3.4us/disp
//  R10: int2-interleaved CSR (halves scatter write-allocate lines)
//  R11: de-atomized scatter (rank from count pass; atomics halved) -29us
//  R12/13: prep_k grid-union (cvt || count_rank overlap)           -6us
//  R14: 2-dispatch scan + folded st-zero                           -6.4us
// REJECTED (measured): launch_bounds min-waves (R3/R6: full spill),
// unroll-2 (R6), inline-asm cvt_pk (R4), readfirstlane scan (R7),
// bf16 LDS u-tile (R4), always-flush scan (R1), 512-block bn grids (R15:
// setup amortization 1:16 -> 1:1.5 beats latency hiding).
#define NBLK64 1536
#define NW64 (NBLK64 * 4)     // 6144 waves
#define B64 (NT / NW64)       // 8
#define R64 (NT % NW64)       // 848

#define NBF 196
#define NWF (NBF * 4)         // 784 waves
#define NBCNT (EE / 256)      // 3125 count blocks (exact)
#define NBPREP (NBF + NBCNT)  // 3321 union blocks

typedef short s8v __attribute__((ext_vector_type(8)));   // 8 x bf16 (4 VGPRs)
typedef float f4v __attribute__((ext_vector_type(4)));   // MFMA C/D

// fp32 -> bf16 RNE via the native __bf16 type (R9 win)
__device__ __forceinline__ short f2bf(float f) {
    __bf16 h = (__bf16)f;
    return __builtin_bit_cast(short, h);
}

// monotone fp32 <-> uint encode for atomicMax-based segment max.
__device__ __forceinline__ unsigned enc(float f) {
    unsigned u = __float_as_uint(f);
    return (u & 0x80000000u) ? ~u : (u | 0x80000000u);
}
__device__ __forceinline__ float dec(unsigned k) {
    if (k == 0u) return 0.0f;                            // empty segment -> 0
    unsigned u = (k & 0x80000000u) ? (k & 0x7fffffffu) : ~k;
    return __uint_as_float(u);
}

// mish(x) = x * (e^{2x}+2e^x) / (e^{2x}+2e^x+2); guard large x
__device__ __forceinline__ float mish_fast(float v) {
    float t = __expf(v);
    float s = t * (t + 2.0f);
    float r = v * s * __builtin_amdgcn_rcpf(s + 2.0f);
    return (v > 15.0f) ? v : r;
}

#define MFMA16(a, b, c) __builtin_amdgcn_mfma_f32_16x16x32_bf16(a, b, c, 0, 0, 0)

// ---------------- CSR build (dst-sorted edge list, int2 interleaved) -------

#define NBS 196                                    // ceil(NN/256)

// per-256-chunk partial sums; block 0 also zeroes the BN-stats accumulator
__global__ __launch_bounds__(256) void scan_part(const int* __restrict__ cnt,
                                                 int* __restrict__ part,
                                                 float* __restrict__ st) {
    int t = threadIdx.x, i = blockIdx.x * 256 + t;
    if (blockIdx.x == 0) {
        st[t] = 0.0f;
        if (t < 128) st[256 + t] = 0.0f;           // 3*128 = 384 floats total
    }
    __shared__ int ps[256];
    ps[t] = (i < NN) ? cnt[i] : 0;
    __syncthreads();
    for (int off = 128; off > 0; off >>= 1) {
        if (t < off) ps[t] += ps[t + off];
        __syncthreads();
    }
    if (t == 0) part[blockIdx.x] = ps[0];
}

// R14: scan_top folded in -- every block recomputes the 196-partial prefix
__global__ __launch_bounds__(256) void scan_fin(const int* __restrict__ cnt,
                                                const int* __restrict__ part,
                                                int* __restrict__ row_off) {
    int t = threadIdx.x, i = blockIdx.x * 256 + t;
    __shared__ int pp[256];
    pp[t] = (t < NBS) ? part[t] : 0;
    __syncthreads();
    for (int off = 1; off < 256; off <<= 1) {
        int u = (t >= off) ? pp[t - off] : 0;
        __syncthreads();
        pp[t] += u;
        __syncthreads();
    }
    const int base = (blockIdx.x == 0) ? 0 : pp[blockIdx.x - 1];  // excl prefix

    int v = (i < NN) ? cnt[i] : 0;
    __shared__ int ps[256];
    ps[t] = v;
    __syncthreads();
    for (int off = 1; off < 256; off <<= 1) {
        int u = (t >= off) ? ps[t - off] : 0;
        __syncthreads();
        ps[t] += u;
        __syncthreads();
    }
    int excl = ps[t] - v + base;
    if (i < NN) row_off[i] = excl;
}

// atomic-FREE scatter: position from cached row_off + precomputed rank (R11)
__global__ __launch_bounds__(256) void scatter_k(const int* __restrict__ ei,
                                                 const int* __restrict__ row_off,
                                                 const int* __restrict__ rank,
                                                 int2* __restrict__ csr_sd) {
    int e = blockIdx.x * 256 + threadIdx.x;
    if (e < EE) {
        int d = ei[EE + e];
        int p = row_off[d] + rank[e];
        int2 v;
        v.x = ei[e];                               // src
        v.y = d;                                   // dst
        csr_sd[p] = v;
    }
}

// -------- R12 grid-union: cvt_a0 (blocks < NBF) U count_rank (rest) --------

__global__ __launch_bounds__(256)
void prep_k(const float* __restrict__ x, const float* __restrict__ w1,
            const float* __restrict__ b1, const int* __restrict__ ei,
            unsigned short* __restrict__ xb, float* __restrict__ a0,
            unsigned* __restrict__ y, unsigned* __restrict__ y8,
            int* __restrict__ cnt, int* __restrict__ rank) {
    const int tid = threadIdx.x;

    if (blockIdx.x >= NBF) {                       // ---- count_rank path ----
        int e = (blockIdx.x - NBF) * 256 + tid;    // < EE exactly (3125*256)
        rank[e] = atomicAdd(&cnt[ei[EE + e]], 1);
        return;
    }

    // ---- cvt_a0 path ----
    const int lane = tid & 63;
    const int wid = blockIdx.x * 4 + (tid >> 6);
    const int i = lane & 15, q = lane >> 4;
    s8v wf[4][2];
#pragma unroll
    for (int nb = 0; nb < 4; nb++)
#pragma unroll
        for (int kh = 0; kh < 2; kh++)
#pragma unroll
            for (int j = 0; j < 8; j++) {
                int k = kh * 32 + q * 8 + j, n = nb * 16 + i;
                wf[nb][kh][j] = f2bf(w1[k * 64 + n] - w1[(64 + k) * 64 + n]);
            }
    float bia[4];
#pragma unroll
    for (int nb = 0; nb < 4; nb++) bia[nb] = b1[nb * 16 + i];

    for (int t = wid; t < NTN; t += NWF) {
        const int row = t * 16 + i;
        const float* xr = x + (size_t)row * 64 + q * 8;
        f4v x0 = *(const f4v*)xr,        f1 = *(const f4v*)(xr + 4);
        f4v x2 = *(const f4v*)(xr + 32), x3 = *(const f4v*)(xr + 36);
        s8v af0, af1;
#pragma unroll
        for (int j = 0; j < 4; j++) {
            af0[j] = f2bf(x0[j]); af0[4 + j] = f2bf(f1[j]);
            af1[j] = f2bf(x2[j]); af1[4 + j] = f2bf(x3[j]);
        }
        unsigned short* xw = xb + (size_t)row * 64 + q * 8;
        *(s8v*)xw = af0;
        *(s8v*)(xw + 32) = af1;
        const int rowq = t * 16 + q * 4;
#pragma unroll
        for (int nb = 0; nb < 4; nb++) {
            f4v c = {0.f, 0.f, 0.f, 0.f};
            c = MFMA16(af0, wf[nb][0], c);
            c = MFMA16(af1, wf[nb][1], c);
#pragma unroll
            for (int r = 0; r < 4; r++)
                a0[(size_t)(rowq + r) * 64 + i * 4 + nb] = c[r] + bia[nb];
        }
    }
    // zero the atomic-max accumulators (uint4)
    const int gt = blockIdx.x * 256 + tid, gs = NBF * 256;
    const uint4 z4 = {0u, 0u, 0u, 0u};
    uint4* y4 = (uint4*)y;
    uint4* y84 = (uint4*)y8;
    for (int idx = gt; idx < NN * 16; idx += gs) y4[idx] = z4;   // NN*64 uints
    for (int idx = gt; idx < NN * 2; idx += gs)  y84[idx] = z4;  // NN*8 uints
}

// -------- fused BN apply + bf16 emit + NEXT layer's a0 GEMM + y re-zero ----

__global__ __launch_bounds__(256)
void bn_a0_64(unsigned* __restrict__ yk, const float* __restrict__ st,
              const float* __restrict__ g, const float* __restrict__ be,
              const float* __restrict__ w1n, const float* __restrict__ b1n,
              unsigned short* __restrict__ xbout, float* __restrict__ a0out) {
    __shared__ float sa[64], sb[64];
    const int tid = threadIdx.x;
    if (tid < 64) {
        float mu  = st[tid] * (1.0f / NN);
        float var = st[64 + tid] * (1.0f / NN) - mu * mu;
        float sc  = rsqrtf(var + 1e-5f) * g[tid];
        sa[tid] = sc;
        sb[tid] = be[tid] - mu * sc;
    }
    __syncthreads();
    const int lane = tid & 63;
    const int wid = blockIdx.x * 4 + (tid >> 6);
    const int i = lane & 15, q = lane >> 4;

    s8v wf[4][2];
#pragma unroll
    for (int nb = 0; nb < 4; nb++)
#pragma unroll
        for (int kh = 0; kh < 2; kh++)
#pragma unroll
            for (int j = 0; j < 8; j++) {
                int k = kh * 32 + q * 8 + j, n = nb * 16 + i;
                wf[nb][kh][j] = f2bf(w1n[k * 64 + n] - w1n[(64 + k) * 64 + n]);
            }
    float bia[4];
#pragma unroll
    for (int nb = 0; nb < 4; nb++) bia[nb] = b1n[nb * 16 + i];

    // per-lane norm constants for its 16 channels (k = kh*32 + q*8 + j)
    f4v a00 = *(const f4v*)(sa + q * 8),      a01 = *(const f4v*)(sa + q * 8 + 4);
    f4v a10 = *(const f4v*)(sa + 32 + q * 8), a11 = *(const f4v*)(sa + 36 + q * 8);
    f4v b00 = *(const f4v*)(sb + q * 8),      b01 = *(const f4v*)(sb + q * 8 + 4);
    f4v b10 = *(const f4v*)(sb + 32 + q * 8), b11 = *(const f4v*)(sb + 36 + q * 8);

    const uint4 z4 = {0u, 0u, 0u, 0u};
    for (int t = wid; t < NTN; t += NWF) {
        const int row = t * 16 + i;
        unsigned* yr = yk + (size_t)row * 64 + q * 8;
        uint4 u0 = *(const uint4*)yr,        u1 = *(const uint4*)(yr + 4);
        uint4 u2 = *(const uint4*)(yr + 32), u3 = *(const uint4*)(yr + 36);
        s8v af0, af1;
        af0[0] = f2bf(dec(u0.x) * a00[0] + b00[0]);
        af0[1] = f2bf(dec(u0.y) * a00[1] + b00[1]);
        af0[2] = f2bf(dec(u0.z) * a00[2] + b00[2]);
        af0[3] = f2bf(dec(u0.w) * a00[3] + b00[3]);
        af0[4] = f2bf(dec(u1.x) * a01[0] + b01[0]);
        af0[5] = f2bf(dec(u1.y) * a01[1] + b01[1]);
        af0[6] = f2bf(dec(u1.z) * a01[2] + b01[2]);
        af0[7] = f2bf(dec(u1.w) * a01[3] + b01[3]);
        af1[0] = f2bf(dec(u2.x) * a10[0] + b10[0]);
        af1[1] = f2bf(dec(u2.y) * a10[1] + b10[1]);
        af1[2] = f2bf(dec(u2.z) * a10[2] + b10[2]);
        af1[3] = f2bf(dec(u2.w) * a10[3] + b10[3]);
        af1[4] = f2bf(dec(u3.x) * a11[0] + b11[0]);
        af1[5] = f2bf(dec(u3.y) * a11[1] + b11[1]);
        af1[6] = f2bf(dec(u3.z) * a11[2] + b11[2]);
        af1[7] = f2bf(dec(u3.w) * a11[3] + b11[3]);

        unsigned short* xw = xbout + (size_t)row * 64 + q * 8;
        *(s8v*)xw = af0;
        *(s8v*)(xw + 32) = af1;
        *(uint4*)yr = z4;        *(uint4*)(yr + 4) = z4;    // re-zero for next layer
        *(uint4*)(yr + 32) = z4; *(uint4*)(yr + 36) = z4;

        const int rowq = t * 16 + q * 4;
#pragma unroll
        for (int nb = 0; nb < 4; nb++) {
            f4v c = {0.f, 0.f, 0.f, 0.f};
            c = MFMA16(af0, wf[nb][0], c);
            c = MFMA16(af1, wf[nb][1], c);
#pragma unroll
            for (int r = 0; r < 4; r++)
                a0out[(size_t)(rowq + r) * 64 + i * 4 + nb] = c[r] + bia[nb];
        }
    }
}

// variant for layer 2 -> 3: next layer dout = 8

__global__ __launch_bounds__(256)
void bn_a0_8(unsigned* __restrict__ yk, const float* __restrict__ st,
             const float* __restrict__ g, const float* __restrict__ be,
             const float* __restrict__ w1n, const float* __restrict__ b1n,
             unsigned short* __restrict__ xbout, float* __restrict__ a08) {
    __shared__ float sa[64], sb[64];
    const int tid = threadIdx.x;
    if (tid < 64) {
        float mu  = st[tid] * (1.0f / NN);
        float var = st[64 + tid] * (1.0f / NN) - mu * mu;
        float sc  = rsqrtf(var + 1e-5f) * g[tid];
        sa[tid] = sc;
        sb[tid] = be[tid] - mu * sc;
    }
    __syncthreads();
    const int lane = tid & 63;
    const int wid = blockIdx.x * 4 + (tid >> 6);
    const int i = lane & 15, q = lane >> 4;

    s8v wf[2];
#pragma unroll
    for (int kh = 0; kh < 2; kh++)
#pragma unroll
        for (int j = 0; j < 8; j++) {
            int k = kh * 32 + q * 8 + j;
            wf[kh][j] = (i < 8) ? f2bf(w1n[k * 8 + i] - w1n[(64 + k) * 8 + i]) : (short)0;
        }
    const float bia = (i < 8) ? b1n[i] : 0.0f;

    f4v a00 = *(const f4v*)(sa + q * 8),      a01 = *(const f4v*)(sa + q * 8 + 4);
    f4v a10 = *(const f4v*)(sa + 32 + q * 8), a11 = *(const f4v*)(sa + 36 + q * 8);
    f4v b00 = *(const f4v*)(sb + q * 8),      b01 = *(const f4v*)(sb + q * 8 + 4);
    f4v b10 = *(const f4v*)(sb + 32 + q * 8), b11 = *(const f4v*)(sb + 36 + q * 8);

    for (int t = wid; t < NTN; t += NWF) {
        const int row = t * 16 + i;
        const unsigned* yr = yk + (size_t)row * 64 + q * 8;
        uint4 u0 = *(const uint4*)yr,        u1 = *(const uint4*)(yr + 4);
        uint4 u2 = *(const uint4*)(yr + 32), u3 = *(const uint4*)(yr + 36);
        s8v af0, af1;
        af0[0] = f2bf(dec(u0.x) * a00[0] + b00[0]);
        af0[1] = f2bf(dec(u0.y) * a00[1] + b00[1]);
        af0[2] = f2bf(dec(u0.z) * a00[2] + b00[2]);
        af0[3] = f2bf(dec(u0.w) * a00[3] + b00[3]);
        af0[4] = f2bf(dec(u1.x) * a01[0] + b01[0]);
        af0[5] = f2bf(dec(u1.y) * a01[1] + b01[1]);
        af0[6] = f2bf(dec(u1.z) * a01[2] + b01[2]);
        af0[7] = f2bf(dec(u1.w) * a01[3] + b01[3]);
        af1[0] = f2bf(dec(u2.x) * a10[0] + b10[0]);
        af1[1] = f2bf(dec(u2.y) * a10[1] + b10[1]);
        af1[2] = f2bf(dec(u2.z) * a10[2] + b10[2]);
        af1[3] = f2bf(dec(u2.w) * a10[3] + b10[3]);
        af1[4] = f2bf(dec(u3.x) * a11[0] + b11[0]);
        af1[5] = f2bf(dec(u3.y) * a11[1] + b11[1]);
        af1[6] = f2bf(dec(u3.z) * a11[2] + b11[2]);
        af1[7] = f2bf(dec(u3.w) * a11[3] + b11[3]);

        unsigned short* xw = xbout + (size_t)row * 64 + q * 8;
        *(s8v*)xw = af0;
        *(s8v*)(xw + 32) = af1;

        f4v c = {0.f, 0.f, 0.f, 0.f};
        c = MFMA16(af0, wf[0], c);
        c = MFMA16(af1, wf[1], c);
        if (i < 8) {
            const int rowq = t * 16 + q * 4;
#pragma unroll
            for (int r = 0; r < 4; r++)
                a08[(size_t)(rowq + r) * 8 + i] = c[r] + bia;
        }
    }
}

// ------- edge-major fused MLP + segmented max, dout=64 (FROZEN R10) -------

__global__ __launch_bounds__(256)
void edge_mfma64(const unsigned short* __restrict__ xb, const float* __restrict__ a0,
                 const float* __restrict__ w1, const float* __restrict__ w2,
                 const float* __restrict__ b2,
                 const int2* __restrict__ csr_sd,
                 unsigned* __restrict__ y) {
    __shared__ float uld[4][16 * 68];                 // per-wave tile, stride 68
    __shared__ int dseg[4][2][20];                    // per-wave dst ids, dbuf
    __shared__ short w2l[8 * 64 * 8];                 // W2 frags: (nb*2+kh, lane, j)
    const int lane = threadIdx.x & 63;
    const int wv = threadIdx.x >> 6;
    const int wid = blockIdx.x * 4 + wv;
    const int i = lane & 15, q = lane >> 4;
    float* up = &uld[wv][0];
    float* spw = up;                                  // 4x64 partials alias (safe)

    // W1bot fragments stay register-resident (32 VGPRs)
    s8v w1f[4][2];
#pragma unroll
    for (int nb = 0; nb < 4; nb++)
#pragma unroll
        for (int kh = 0; kh < 2; kh++)
#pragma unroll
            for (int j = 0; j < 8; j++) {
                int k = kh * 32 + q * 8 + j, n = nb * 16 + i;
                w1f[nb][kh][j] = f2bf(w1[(64 + k) * 64 + n]);
            }
    // stage this wave's nb(=wv) W2 fragments into shared LDS
    {
        const int nb = wv;
#pragma unroll
        for (int kh = 0; kh < 2; kh++) {
            s8v uu;
#pragma unroll
            for (int j = 0; j < 8; j++) {
                int k = kh * 32 + q * 8 + j;
                uu[j] = f2bf(w2[k * 64 + nb * 16 + i]);
            }
            *(s8v*)(w2l + ((nb * 2 + kh) * 64 + lane) * 8) = uu;
        }
    }
    __syncthreads();

    const float b2s = b2[lane];                       // wave-scan channel = lane
    const float b2n0 = b2[i],      b2n1 = b2[16 + i]; // interior-flush channels
    const float b2n2 = b2[32 + i], b2n3 = b2[48 + i];

    // balanced partition: first R64 waves get B64+1 tiles, rest B64
    int t = wid * B64 + (wid < R64 ? wid : R64);
    const int tend = t + B64 + (wid < R64 ? 1 : 0);

    s8v af0_c, af1_c;
    {
        int s0 = csr_sd[t * 16 + i].x;
        const unsigned short* xr = xb + (size_t)s0 * 64;
        af0_c = *(const s8v*)(xr + q * 8);
        af1_c = *(const s8v*)(xr + 32 + q * 8);
    }
    int src_n = (t + 1 < tend) ? csr_sd[(t + 1) * 16 + i].x : 0;
    if (lane < 16) dseg[wv][t & 1][lane] = csr_sd[t * 16 + lane].y;
    asm volatile("s_waitcnt lgkmcnt(0)" ::: "memory");
    int dq_c[4];
#pragma unroll
    for (int r = 0; r < 4; r++) dq_c[r] = dseg[wv][t & 1][q * 4 + r];
    f4v a0r_c[4];
#pragma unroll
    for (int r = 0; r < 4; r++)
        a0r_c[r] = *(const f4v*)(a0 + (size_t)dq_c[r] * 64 + i * 4);

    // carried wave-scan state (channel = lane)
    float runC = -INFINITY;
    int dcC = dseg[wv][t & 1][0];

    for (; t < tend; t++) {
        const bool has_n = (t + 1) < tend;
        const int* dsg = &dseg[wv][t & 1][0];
        int* dsg_n = &dseg[wv][(t + 1) & 1][0];

        if (has_n && lane < 16) dsg_n[lane] = csr_sd[(t + 1) * 16 + lane].y;

        s8v af0_n = {0,0,0,0,0,0,0,0}, af1_n = {0,0,0,0,0,0,0,0};
        if (has_n) {
            const unsigned short* xr = xb + (size_t)src_n * 64;
            af0_n = *(const s8v*)(xr + q * 8);
            af1_n = *(const s8v*)(xr + 32 + q * 8);
        }
        int src_nn = (t + 2 < tend) ? csr_sd[(t + 2) * 16 + i].x : 0;

        // GEMM1
        f4v c0 = {0.f, 0.f, 0.f, 0.f}, c1 = c0, c2 = c0, c3 = c0;
        c0 = MFMA16(af0_c, w1f[0][0], c0); c0 = MFMA16(af1_c, w1f[0][1], c0);
        c1 = MFMA16(af0_c, w1f[1][0], c1); c1 = MFMA16(af1_c, w1f[1][1], c1);
        c2 = MFMA16(af0_c, w1f[2][0], c2); c2 = MFMA16(af1_c, w1f[2][1], c2);
        c3 = MFMA16(af0_c, w1f[3][0], c3); c3 = MFMA16(af1_c, w1f[3][1], c3);

        asm volatile("" ::: "memory");
        // stage-1: mish -> fp32 tile (R0 verbatim)
#pragma unroll
        for (int r = 0; r < 4; r++) {
            const int ro = (q * 4 + r) * 68 + i;
            up[ro +  0] = mish_fast(c0[r] + a0r_c[r][0]);
            up[ro + 16] = mish_fast(c1[r] + a0r_c[r][1]);
            up[ro + 32] = mish_fast(c2[r] + a0r_c[r][2]);
            up[ro + 48] = mish_fast(c3[r] + a0r_c[r][3]);
        }
        asm volatile("s_waitcnt lgkmcnt(0)" ::: "memory");   // stage1 + dsg_n visible

        int dq_n[4];
        f4v a0r_n[4];
        if (has_n) {
#pragma unroll
            for (int r = 0; r < 4; r++) dq_n[r] = dsg_n[q * 4 + r];
#pragma unroll
            for (int r = 0; r < 4; r++)
                a0r_n[r] = *(const f4v*)(a0 + (size_t)dq_n[r] * 64 + i * 4);
        }

        s8v uf[2];
#pragma unroll
        for (int kh = 0; kh < 2; kh++) {
            const f4v* rp = (const f4v*)(up + i * 68 + kh * 32 + q * 8);
            f4v v0 = rp[0], v1 = rp[1];
            s8v uu;
            uu[0] = f2bf(v0[0]); uu[1] = f2bf(v0[1]);
            uu[2] = f2bf(v0[2]); uu[3] = f2bf(v0[3]);
            uu[4] = f2bf(v1[0]); uu[5] = f2bf(v1[1]);
            uu[6] = f2bf(v1[2]); uu[7] = f2bf(v1[3]);
            uf[kh] = uu;
        }
        asm volatile("" ::: "memory");

        // GEMM2 (B fragments streamed from shared LDS); output stays in regs
        f4v cc[4];
#pragma unroll
        for (int nb = 0; nb < 4; nb++) {
            s8v b0 = *(const s8v*)(w2l + ((nb * 2 + 0) * 64 + lane) * 8);
            s8v b1v = *(const s8v*)(w2l + ((nb * 2 + 1) * 64 + lane) * 8);
            f4v c = {0.f, 0.f, 0.f, 0.f};
            c = MFMA16(uf[0], b0, c);
            c = MFMA16(uf[1], b1v, c);
            cc[nb] = c;
        }

        // in-register segmented reduce over this lane's 4 consecutive rows;
        // interior segment ends (rare) flush directly.
        float r0 = cc[0][0], r1 = cc[1][0], r2 = cc[2][0], r3 = cc[3][0];

#define SCAN_STEP(RR)                                                        \
        {                                                                    \
            bool mm = (dq_c[RR] != dq_c[RR - 1]);                            \
            if (__any(mm)) {                                                 \
                if (mm) {                                                    \
                    size_t bse = (size_t)dq_c[RR - 1] * 64 + i;              \
                    atomicMax(&y[bse],      enc(r0 + b2n0));                 \
                    atomicMax(&y[bse + 16], enc(r1 + b2n1));                 \
                    atomicMax(&y[bse + 32], enc(r2 + b2n2));                 \
                    atomicMax(&y[bse + 48], enc(r3 + b2n3));                 \
                }                                                            \
                r0 = mm ? cc[0][RR] : fmaxf(r0, cc[0][RR]);                  \
                r1 = mm ? cc[1][RR] : fmaxf(r1, cc[1][RR]);                  \
                r2 = mm ? cc[2][RR] : fmaxf(r2, cc[2][RR]);                  \
                r3 = mm ? cc[3][RR] : fmaxf(r3, cc[3][RR]);                  \
            } else {                                                         \
                r0 = fmaxf(r0, cc[0][RR]); r1 = fmaxf(r1, cc[1][RR]);        \
                r2 = fmaxf(r2, cc[2][RR]); r3 = fmaxf(r3, cc[3][RR]);        \
            }                                                                \
        }
        SCAN_STEP(1)
        SCAN_STEP(2)
        SCAN_STEP(3)
#undef SCAN_STEP

        // suffix partials -> 4x64 tile (aliases up: uf reads precede these
        // writes in program order; DS is in-order per wave), then carried
        // 4-step wave scan (channel = lane).
        spw[q * 68 +       i] = r0;
        spw[q * 68 + 16 +  i] = r1;
        spw[q * 68 + 32 +  i] = r2;
        spw[q * 68 + 48 +  i] = r3;
        asm volatile("s_waitcnt lgkmcnt(0)" ::: "memory");

        float v0 = spw[lane],        v1 = spw[68 + lane];
        float v2s = spw[136 + lane], v3s = spw[204 + lane];
        int e0 = dsg[3], e1 = dsg[7], e2 = dsg[11], e3 = dsg[15];

        if (e0 != dcC) {
            atomicMax(&y[(size_t)dcC * 64 + lane], enc(runC + b2s));
            runC = v0; dcC = e0;
        } else runC = fmaxf(runC, v0);
        if (e1 != dcC) {
            atomicMax(&y[(size_t)dcC * 64 + lane], enc(runC + b2s));
            runC = v1; dcC = e1;
        } else runC = fmaxf(runC, v1);
        if (e2 != dcC) {
            atomicMax(&y[(size_t)dcC * 64 + lane], enc(runC + b2s));
            runC = v2s; dcC = e2;
        } else runC = fmaxf(runC, v2s);
        if (e3 != dcC) {
            atomicMax(&y[(size_t)dcC * 64 + lane], enc(runC + b2s));
            runC = v3s; dcC = e3;
        } else runC = fmaxf(runC, v3s);
        asm volatile("s_waitcnt lgkmcnt(0)" ::: "memory");        // WAR guard

        src_n = src_nn;
        af0_c = af0_n; af1_c = af1_n;
#pragma unroll
        for (int r = 0; r < 4; r++) { dq_c[r] = dq_n[r]; a0r_c[r] = a0r_n[r]; }
    }
    // final flush of carried run
    atomicMax(&y[(size_t)dcC * 64 + lane], enc(runC + b2s));
}

// ------- edge-major final layer, dout=8 (FROZEN R10) -------

__global__ __launch_bounds__(256)
void edge_mfma16(const unsigned short* __restrict__ xb, const float* __restrict__ a0,
                 const float* __restrict__ w1, const float* __restrict__ w2,
                 const float* __restrict__ b2,
                 const int2* __restrict__ csr_sd,
                 unsigned* __restrict__ y8) {
    __shared__ float uld[4][16 * 20];
    __shared__ int dseg[4][2][16];
    const int lane = threadIdx.x & 63;
    const int wv = threadIdx.x >> 6;
    const int wid = blockIdx.x * 4 + wv;
    const int i = lane & 15, q = lane >> 4;
    float* up = &uld[wv][0];
    float* spw = up;                                  // 4x8 partials alias

    s8v w1f[2], w2f;
#pragma unroll
    for (int kh = 0; kh < 2; kh++)
#pragma unroll
        for (int j = 0; j < 8; j++) {
            int k = kh * 32 + q * 8 + j;
            w1f[kh][j] = (i < 8) ? f2bf(w1[(64 + k) * 8 + i]) : (short)0;
        }
#pragma unroll
    for (int j = 0; j < 8; j++)
        w2f[j] = (q == 0 && i < 8) ? f2bf(w2[j * 8 + i]) : (short)0;
    const float b2c = (lane < 8) ? b2[lane] : 0.0f;   // wave-scan channel
    const float b2n = (i < 8) ? b2[i] : 0.0f;         // interior-flush channel

    // balanced partition: first R64 waves get B64+1 tiles, rest B64
    int t = wid * B64 + (wid < R64 ? wid : R64);
    const int tend = t + B64 + (wid < R64 ? 1 : 0);

    s8v af0_c, af1_c;
    {
        int s0 = csr_sd[t * 16 + i].x;
        const unsigned short* xr = xb + (size_t)s0 * 64;
        af0_c = *(const s8v*)(xr + q * 8);
        af1_c = *(const s8v*)(xr + 32 + q * 8);
    }
    int src_n = (t + 1 < tend) ? csr_sd[(t + 1) * 16 + i].x : 0;
    if (lane < 16) dseg[wv][t & 1][lane] = csr_sd[t * 16 + lane].y;
    asm volatile("s_waitcnt lgkmcnt(0)" ::: "memory");
    int dq_c[4];
#pragma unroll
    for (int r = 0; r < 4; r++) dq_c[r] = dseg[wv][t & 1][q * 4 + r];
    float av_c[4];
#pragma unroll
    for (int r = 0; r < 4; r++)
        av_c[r] = (i < 8) ? a0[(size_t)dq_c[r] * 8 + i] : 0.0f;

    // carried wave-scan state (channel = lane&7, lanes<8 own the atomics)
    float runC = -INFINITY;
    int dcC = dseg[wv][t & 1][0];

    for (; t < tend; t++) {
        const bool has_n = (t + 1) < tend;
        const int* dsg = &dseg[wv][t & 1][0];
        int* dsg_n = &dseg[wv][(t + 1) & 1][0];

        if (has_n && lane < 16) dsg_n[lane] = csr_sd[(t + 1) * 16 + lane].y;

        s8v af0_n = {0,0,0,0,0,0,0,0}, af1_n = {0,0,0,0,0,0,0,0};
        if (has_n) {
            const unsigned short* xr = xb + (size_t)src_n * 64;
            af0_n = *(const s8v*)(xr + q * 8);
            af1_n = *(const s8v*)(xr + 32 + q * 8);
        }
        int src_nn = (t + 2 < tend) ? csr_sd[(t + 2) * 16 + i].x : 0;

        f4v c = {0.f, 0.f, 0.f, 0.f};
        c = MFMA16(af0_c, w1f[0], c);
        c = MFMA16(af1_c, w1f[1], c);

        asm volatile("" ::: "memory");
#pragma unroll
        for (int r = 0; r < 4; r++)
            up[(q * 4 + r) * 20 + i] = mish_fast(c[r] + av_c[r]);   // cols 8..15 = 0
        asm volatile("s_waitcnt lgkmcnt(0)" ::: "memory");           // wait#2

        int dq_n[4];
        float av_n[4] = {0, 0, 0, 0};
        if (has_n) {
#pragma unroll
            for (int r = 0; r < 4; r++) dq_n[r] = dsg_n[q * 4 + r];
#pragma unroll
            for (int r = 0; r < 4; r++)
                av_n[r] = (i < 8) ? a0[(size_t)dq_n[r] * 8 + i] : 0.0f;
        }

        s8v uf = {0,0,0,0,0,0,0,0};
        if (q < 2) {                                   // k = q*8+j < 16
            const f4v* rp = (const f4v*)(up + i * 20 + q * 8);
            f4v v0 = rp[0], v1 = rp[1];
            uf[0] = f2bf(v0[0]); uf[1] = f2bf(v0[1]);
            uf[2] = f2bf(v0[2]); uf[3] = f2bf(v0[3]);
            uf[4] = f2bf(v1[0]); uf[5] = f2bf(v1[1]);
            uf[6] = f2bf(v1[2]); uf[7] = f2bf(v1[3]);
        }
        asm volatile("" ::: "memory");

        f4v cc = {0.f, 0.f, 0.f, 0.f};
        cc = MFMA16(uf, w2f, cc);

        // in-register segmented reduce over this lane's 4 rows (ch = i, i<8)
        float r0 = cc[0];
#define SCAN16(RR)                                                           \
        {                                                                    \
            bool mm = (dq_c[RR] != dq_c[RR - 1]);                            \
            if (__any(mm)) {                                                 \
                if (mm && i < 8)                                             \
                    atomicMax(&y8[(size_t)dq_c[RR - 1] * 8 + i],             \
                              enc(r0 + b2n));                                \
                r0 = mm ? cc[RR] : fmaxf(r0, cc[RR]);                        \
            } else r0 = fmaxf(r0, cc[RR]);                                   \
        }
        SCAN16(1)
        SCAN16(2)
        SCAN16(3)
#undef SCAN16

        // suffix partial -> 4x8 tile (alias up rows 0-3), carried wave scan
        spw[q * 20 + i] = r0;
        asm volatile("s_waitcnt lgkmcnt(0)" ::: "memory");

        float v0 = spw[lane & 7],      v1 = spw[20 + (lane & 7)];
        float v2 = spw[40 + (lane & 7)], v3 = spw[60 + (lane & 7)];
        int e0 = dsg[3], e1 = dsg[7], e2 = dsg[11], e3 = dsg[15];

        if (e0 != dcC) {
            if (lane < 8) atomicMax(&y8[(size_t)dcC * 8 + lane], enc(runC + b2c));
            runC = v0; dcC = e0;
        } else runC = fmaxf(runC, v0);
        if (e1 != dcC) {
            if (lane < 8) atomicMax(&y8[(size_t)dcC * 8 + lane], enc(runC + b2c));
            runC = v1; dcC = e1;
        } else runC = fmaxf(runC, v1);
        if (e2 != dcC) {
            if (lane < 8) atomicMax(&y8[(size_t)dcC * 8 + lane], enc(runC + b2c));
            runC = v2; dcC = e2;
        } else runC = fmaxf(runC, v2);
        if (e3 != dcC) {
            if (lane < 8) atomicMax(&y8[(size_t)dcC * 8 + lane], enc(runC + b2c));
            runC = v3; dcC = e3;
        } else runC = fmaxf(runC, v3);
        asm volatile("s_waitcnt lgkmcnt(0)" ::: "memory");        // WAR guard

        src_n = src_nn;
        af0_c = af0_n; af1_c = af1_n;
#pragma unroll
        for (int r = 0; r < 4; r++) { dq_c[r] = dq_n[r]; av_c[r] = av_n[r]; }
    }
    if (lane < 8)
        atomicMax(&y8[(size_t)dcC * 8 + lane], enc(runC + b2c));
}

// ---------------- BatchNorm stats (R5: uint4-vectorized) ----------------

__global__ __launch_bounds__(256)
void bn_stats(const unsigned* __restrict__ yk, float* __restrict__ st) {
    const int tid = threadIdx.x;
    const int c4 = (tid & 15) * 4;                 // channel group base
    const int grp = tid >> 4;                      // 16 row groups
    float s0 = 0, s1 = 0, s2 = 0, s3 = 0;
    float q0 = 0, q1 = 0, q2 = 0, q3 = 0;
    for (int n = blockIdx.x * 16 + grp; n < NN; n += gridDim.x * 16) {
        uint4 u = *(const uint4*)(yk + (size_t)n * 64 + c4);
        float v0 = dec(u.x), v1 = dec(u.y), v2 = dec(u.z), v3 = dec(u.w);
        s0 += v0; s1 += v1; s2 += v2; s3 += v3;
        q0 = fmaf(v0, v0, q0); q1 = fmaf(v1, v1, q1);
        q2 = fmaf(v2, v2, q2); q3 = fmaf(v3, v3, q3);
    }
    __shared__ float ls[256][4], lq[256][4];
    ls[tid][0] = s0; ls[tid][1] = s1; ls[tid][2] = s2; ls[tid][3] = s3;
    lq[tid][0] = q0; lq[tid][1] = q1; lq[tid][2] = q2; lq[tid][3] = q3;
    __syncthreads();
    if (tid < 64) {
        const int cg = tid >> 2, ce = tid & 3;     // channel = cg*4 + ce
        float ss = 0, qq = 0;
        for (int g = 0; g < 16; g++) {
            ss += ls[g * 16 + cg][ce];
            qq += lq[g * 16 + cg][ce];
        }
        atomicAdd(&st[cg * 4 + ce], ss);
        atomicAdd(&st[64 + cg * 4 + ce], qq);
    }
}

__global__ __launch_bounds__(256)
void decode_out(const unsigned* __restrict__ y8, float* __restrict__ out) {
    int idx = blockIdx.x * 256 + threadIdx.x;
    if (idx < NN * 8) out[idx] = dec(y8[idx]);
}

// ---------------- launch ----------------

extern "C" void kernel_launch(void* const* d_in, const int* in_sizes, int n_in,
                              void* d_out, int out_size, void* d_ws, size_t ws_size,
                              hipStream_t stream) {
    const float* x0 = (const float*)d_in[0];
    const int*   ei = (const int*)d_in[1];
    const float* w1[4] = {(const float*)d_in[3],  (const float*)d_in[9],
                          (const float*)d_in[15], (const float*)d_in[21]};
    const float* b1[4] = {(const float*)d_in[4],  (const float*)d_in[10],
                          (const float*)d_in[16], (const float*)d_in[22]};
    const float* w2[4] = {(const float*)d_in[5],  (const float*)d_in[11],
                          (const float*)d_in[17], (const float*)d_in[23]};
    const float* b2[4] = {(const float*)d_in[6],  (const float*)d_in[12],
                          (const float*)d_in[18], (const float*)d_in[24]};
    const float* gg[3] = {(const float*)d_in[7],  (const float*)d_in[13],
                          (const float*)d_in[19]};
    const float* be[3] = {(const float*)d_in[8],  (const float*)d_in[14],
                          (const float*)d_in[20]};

    char* p = (char*)d_ws;
    auto alloc = [&](size_t bytes) -> char* {
        char* r = p;
        p += (bytes + 255) & ~(size_t)255;
        return r;
    };
    int*      cnt     = (int*)alloc((size_t)NN * 4);
    int*      part    = (int*)alloc((size_t)NBS * 4);
    int*      row_off = (int*)alloc((size_t)(NN + 1) * 4);
    int*      rank    = (int*)alloc((size_t)EE * 4);
    int2*     csr_sd  = (int2*)alloc((size_t)EE * 8);
    float*    st      = (float*)alloc(3 * 128 * 4);
    float*    a0      = (float*)alloc((size_t)NN * 64 * 4);   // reused for a0_8
    unsigned* y       = (unsigned*)alloc((size_t)NN * 64 * 4);
    unsigned* y8      = (unsigned*)alloc((size_t)NN * 8 * 4);
    unsigned short* xb0 = (unsigned short*)alloc((size_t)NN * 64 * 2);
    unsigned short* xbA = (unsigned short*)alloc((size_t)NN * 64 * 2);
    unsigned short* xbB = xb0;

    hipMemsetAsync(cnt, 0, (size_t)NN * 4, stream);

    // R12 union dispatch: cvt_a0 (196 blocks) + count_rank (3125 blocks)
    prep_k<<<NBPREP, 256, 0, stream>>>(x0, w1[0], b1[0], ei, xb0, a0, y, y8,
                                       cnt, rank);

    // R14: 2-dispatch scan
    scan_part<<<NBS, 256, 0, stream>>>(cnt, part, st);
    scan_fin<<<NBS, 256, 0, stream>>>(cnt, part, row_off);
    scatter_k<<<(EE + 255) / 256, 256, 0, stream>>>(ei, row_off, rank, csr_sd);

    // layer 0
    edge_mfma64<<<NBLK64, 256, 0, stream>>>(xb0, a0, w1[0], w2[0], b2[0],
                                            csr_sd, y);
    bn_stats<<<256, 256, 0, stream>>>(y, st);
    bn_a0_64<<<NBF, 256, 0, stream>>>(y, st, gg[0], be[0], w1[1], b1[1], xbA, a0);

    // layer 1
    edge_mfma64<<<NBLK64, 256, 0, stream>>>(xbA, a0, w1[1], w2[1], b2[1],
                                            csr_sd, y);
    bn_stats<<<256, 256, 0, stream>>>(y, st + 128);
    bn_a0_64<<<NBF, 256, 0, stream>>>(y, st + 128, gg[1], be[1], w1[2], b1[2], xbB, a0);

    // layer 2
    edge_mfma64<<<NBLK64, 256, 0, stream>>>(xbB, a0, w1[2], w2[2], b2[2],
                                            csr_sd, y);
    bn_stats<<<256, 256, 0, stream>>>(y, st + 256);
    bn_a0_8<<<NBF, 256, 0, stream>>>(y, st + 256, gg[2], be[2], w1[3], b1[3], xbA, a0);

    // layer 3: xbA -> d_out [N,8]
    edge_mfma16<<<NBLK64, 256, 0, stream>>>(xbA, a0, w1[3], w2[3], b2[3],
                                            csr_sd, y8);
    decode_out<<<(NN * 8 + 255) / 256, 256, 0, stream>>>(y8, (float*)d_out);
}